// Round 4
// baseline (195.866 us; speedup 1.0000x reference)
//
#include <hip/hip_runtime.h>

#define NN 1024
#define EMBED 256
#define HID 128
#define EPS 1e-8f
#define INV_N (1.0f / 1024.0f)
#define LDSPITCH 132  // 128 + 4: breaks power-of-2 LDS row stride, keeps 16B alignment
#define NBLK 512

// ---------------------------------------------------------------------------
// Hand-rolled grid barrier: monotone single counter, three thresholds.
// cg::grid.sync() cost ~30us/sync (coarse s_sleep backoff in __ockl_grid_sync);
// this is the same memory semantics (agent-scope release/acquire around a
// device-scope atomic) with a 64-cycle poll quantum.
// ---------------------------------------------------------------------------
__device__ __forceinline__ void gridbar(unsigned* __restrict__ ctr, unsigned target) {
    __syncthreads();
    if (threadIdx.x == 0) {
        __threadfence();  // agent-scope release: make this block's stores visible
        __hip_atomic_fetch_add(ctr, 1u, __ATOMIC_RELAXED, __HIP_MEMORY_SCOPE_AGENT);
        while (__hip_atomic_load(ctr, __ATOMIC_RELAXED, __HIP_MEMORY_SCOPE_AGENT) < target) {
            __builtin_amdgcn_s_sleep(1);
        }
        __threadfence();  // agent-scope acquire: invalidate stale cached lines
    }
    __syncthreads();
}

// ---------------------------------------------------------------------------
// Init node: zero rowsum[1024] ++ tcol[1024] ++ barrier counter.
// Needed every launch (ws poisoned 0xAA before capture; atomics accumulate).
// ---------------------------------------------------------------------------
__global__ __launch_bounds__(256) void kInit(float* __restrict__ acc, unsigned* __restrict__ ctr) {
    acc[blockIdx.x * 256 + threadIdx.x] = 0.0f;
    if (blockIdx.x == 0 && threadIdx.x == 0) *ctr = 0u;
}

// ---------------------------------------------------------------------------
// Fused kernel: 512 blocks x 256 threads (2 blocks/CU), custom barriers.
// Phase A: hs' = src @ W1[:256] + b1 ; ht = tgt @ W1[256:]   (2+2 rows/block)
// Phase B: 32x64 tile: C[i,j] = relu(hs'[i]+ht[j]).W2 + b2, rowsum(exp(-C))
// Phase C: tcol[j] = sum_i exp(-C[i,j]) * u[i]
// Phase D: plan = u .* exp(-C) .* v
// ---------------------------------------------------------------------------
__global__ __launch_bounds__(256) void fusedNOT(const float* __restrict__ src,
                                                const float* __restrict__ tgt,
                                                const float* __restrict__ W1,
                                                const float* __restrict__ b1,
                                                const float* __restrict__ W2,
                                                const float* __restrict__ b2,
                                                float* __restrict__ plan,
                                                float* __restrict__ Cmat,
                                                float* __restrict__ hsp,
                                                float* __restrict__ htp,
                                                float* __restrict__ rowsum,
                                                float* __restrict__ tcol,
                                                unsigned* __restrict__ barctr) {
    __shared__ float hsL[32 * LDSPITCH];  // 16.9 KB (phase A reuses first 4 KB)
    __shared__ float htL[64 * LDSPITCH];  // 33.8 KB
    __shared__ float w2L[HID];
    __shared__ float rsL[32];

    const int b = blockIdx.x;
    const int tid = threadIdx.x;

    // ---------------- Phase A: 2 src rows + 2 tgt rows per block ----------------
    {
        float* s = hsL;  // [4][256] staging: rows 0-1 src, 2-3 tgt
        const int r0 = b * 2;
        {
            const float4* gs = (const float4*)(src + r0 * EMBED);
            const float4* gt = (const float4*)(tgt + r0 * EMBED);
            float4* sv = (float4*)s;
            if (tid < 128) sv[tid] = gs[tid];              // 2 src rows = 128 float4
            else           sv[tid] = gt[tid - 128];        // 2 tgt rows
        }
        __syncthreads();

        const int h = tid & 127;
        const int rr = tid >> 7;  // 0 or 1
        const float* __restrict__ wsrc = W1;                 // [256][128]
        const float* __restrict__ wtgt = W1 + EMBED * HID;
        const float* __restrict__ ss = &s[rr * EMBED];
        const float* __restrict__ st = &s[(2 + rr) * EMBED];
        float as = 0.f, at = 0.f;

        for (int k = 0; k < EMBED; k += 4) {
            const float ws0 = wsrc[(k + 0) * HID + h];
            const float ws1 = wsrc[(k + 1) * HID + h];
            const float ws2 = wsrc[(k + 2) * HID + h];
            const float ws3 = wsrc[(k + 3) * HID + h];
            const float wt0 = wtgt[(k + 0) * HID + h];
            const float wt1 = wtgt[(k + 1) * HID + h];
            const float wt2 = wtgt[(k + 2) * HID + h];
            const float wt3 = wtgt[(k + 3) * HID + h];
            const float4 vs = *(const float4*)&ss[k];
            const float4 vt = *(const float4*)&st[k];
            as = fmaf(vs.x, ws0, as); as = fmaf(vs.y, ws1, as);
            as = fmaf(vs.z, ws2, as); as = fmaf(vs.w, ws3, as);
            at = fmaf(vt.x, wt0, at); at = fmaf(vt.y, wt1, at);
            at = fmaf(vt.z, wt2, at); at = fmaf(vt.w, wt3, at);
        }

        hsp[(r0 + rr) * HID + h] = as + b1[h];
        htp[(r0 + rr) * HID + h] = at;
    }

    gridbar(barctr, NBLK);

    // ---------------- Phase B: 32(i) x 64(j) tile ----------------
    {
        const int i0 = (b >> 4) * 32;   // 32 i-tiles
        const int j0 = (b & 15) * 64;   // 16 j-tiles

        for (int idx = tid; idx < 32 * 32; idx += 256) {   // hsL: 32 rows
            const int i = idx >> 5;
            const int h4 = (idx & 31) << 2;
            *(float4*)&hsL[i * LDSPITCH + h4] = *(const float4*)&hsp[(i0 + i) * HID + h4];
        }
        for (int idx = tid; idx < 64 * 32; idx += 256) {   // htL: 64 rows
            const int i = idx >> 5;
            const int h4 = (idx & 31) << 2;
            *(float4*)&htL[i * LDSPITCH + h4] = *(const float4*)&htp[(j0 + i) * HID + h4];
        }
        if (tid < HID) w2L[tid] = W2[tid];
        if (tid < 32) rsL[tid] = 0.0f;
        __syncthreads();

        const int ti = tid & 15;
        const int tj = tid >> 4;
        float acc[2][4] = {};

        for (int h = 0; h < HID; h += 4) {
            const float4 A0 = *(const float4*)&hsL[(ti + 0) * LDSPITCH + h];
            const float4 A1 = *(const float4*)&hsL[(ti + 16) * LDSPITCH + h];
            const float4 B0 = *(const float4*)&htL[(tj + 0) * LDSPITCH + h];
            const float4 B1 = *(const float4*)&htL[(tj + 16) * LDSPITCH + h];
            const float4 B2 = *(const float4*)&htL[(tj + 32) * LDSPITCH + h];
            const float4 B3 = *(const float4*)&htL[(tj + 48) * LDSPITCH + h];
            const float4 wv = *(const float4*)&w2L[h];
#define STEP(a, bb, Av, Bv)                                                    \
            {                                                                  \
                float t;                                                       \
                t = Av.x + Bv.x; acc[a][bb] = fmaf(fmaxf(t, 0.f), wv.x, acc[a][bb]); \
                t = Av.y + Bv.y; acc[a][bb] = fmaf(fmaxf(t, 0.f), wv.y, acc[a][bb]); \
                t = Av.z + Bv.z; acc[a][bb] = fmaf(fmaxf(t, 0.f), wv.z, acc[a][bb]); \
                t = Av.w + Bv.w; acc[a][bb] = fmaf(fmaxf(t, 0.f), wv.w, acc[a][bb]); \
            }
            STEP(0, 0, A0, B0) STEP(0, 1, A0, B1) STEP(0, 2, A0, B2) STEP(0, 3, A0, B3)
            STEP(1, 0, A1, B0) STEP(1, 1, A1, B1) STEP(1, 2, A1, B2) STEP(1, 3, A1, B3)
#undef STEP
        }

        const float b2v = b2[0];
        float rp[2] = {0.f, 0.f};
        for (int a = 0; a < 2; ++a) {
            const int i = i0 + ti + 16 * a;
            for (int bb = 0; bb < 4; ++bb) {
                const int j = j0 + tj + 16 * bb;
                const float c = acc[a][bb] + b2v;
                Cmat[i * NN + j] = c;
                rp[a] += expf(-c);
            }
        }
        for (int a = 0; a < 2; ++a) atomicAdd(&rsL[ti + 16 * a], rp[a]);
        __syncthreads();
        if (tid < 32) atomicAdd(&rowsum[i0 + tid], rsL[tid]);
    }

    gridbar(barctr, 2 * NBLK);

    // ---------------- Phase C: tcol[j] = sum_i exp(-C[i,j]) * u[i] ----------------
    {
        const int jb = b & 3;
        const int ic = b >> 2;       // 128 chunks x 8 rows
        const int j = jb * 256 + tid;
        float acc = 0.f;
#pragma unroll
        for (int ii = 0; ii < 8; ++ii) {
            const int i = ic * 8 + ii;
            const float u = INV_N / (INV_N * rowsum[i] + EPS);
            const float c = Cmat[i * NN + j];
            acc = fmaf(expf(-c), u, acc);
        }
        atomicAdd(&tcol[j], acc);
    }

    gridbar(barctr, 3 * NBLK);

    // ---------------- Phase D: plan = u .* exp(-C) .* v ----------------
    {
        const int i0 = b * 2;
        const int j4 = tid * 4;
        const float4 t4 = *(const float4*)&tcol[j4];
        float4 v4;
        v4.x = INV_N / (t4.x + EPS);
        v4.y = INV_N / (t4.y + EPS);
        v4.z = INV_N / (t4.z + EPS);
        v4.w = INV_N / (t4.w + EPS);
#pragma unroll
        for (int r = 0; r < 2; ++r) {
            const int row = i0 + r;
            const float u = INV_N / (INV_N * rowsum[row] + EPS);
            const float4 c4 = *(const float4*)&Cmat[row * NN + j4];
            float4 p;
            p.x = u * expf(-c4.x) * v4.x;
            p.y = u * expf(-c4.y) * v4.y;
            p.z = u * expf(-c4.z) * v4.z;
            p.w = u * expf(-c4.w) * v4.w;
            *(float4*)&plan[row * NN + j4] = p;
        }
    }
}

// ---------------------------------------------------------------------------
extern "C" void kernel_launch(void* const* d_in, const int* in_sizes, int n_in,
                              void* d_out, int out_size, void* d_ws, size_t ws_size,
                              hipStream_t stream) {
    const float* src = (const float*)d_in[0];   // [1024, 256]
    const float* tgt = (const float*)d_in[1];   // [1024, 256]
    const float* W1  = (const float*)d_in[2];   // [512, 128]
    const float* b1  = (const float*)d_in[3];   // [128]
    const float* W2  = (const float*)d_in[4];   // [128, 1]
    const float* b2  = (const float*)d_in[5];   // [1]

    float* out = (float*)d_out;
    float* plan = out;            // [1024, 1024] (output 0)
    float* Cmat = out + NN * NN;  // [1024, 1024] (output 1)

    float* ws = (float*)d_ws;
    float* hsp    = ws;                      // [1024][128]
    float* htp    = ws + NN * HID;           // [1024][128]
    float* rowsum = ws + 2 * NN * HID;       // [1024]
    float* tcol   = rowsum + NN;             // [1024]
    unsigned* barctr = (unsigned*)(tcol + NN);  // [1]

    kInit<<<8, 256, 0, stream>>>(rowsum, barctr);

    void* args[] = {(void*)&src, (void*)&tgt, (void*)&W1, (void*)&b1,
                    (void*)&W2, (void*)&b2, (void*)&plan, (void*)&Cmat,
                    (void*)&hsp, (void*)&htp, (void*)&rowsum, (void*)&tcol,
                    (void*)&barctr};
    hipLaunchCooperativeKernel((void*)fusedNOT, dim3(NBLK), dim3(256), args, 0, stream);
}

// Round 5
// 38.128 us; speedup vs baseline: 5.1370x; 5.1370x over previous
//
#include <hip/hip_runtime.h>

#define NN 1024
#define EMBED 256
#define HID 128
#define EPS 1e-8f
#define NEPS (1.024e-5f)   // NN * EPS:  INV_N/(INV_N*r + EPS) == 1/(r + NN*EPS)
#define INV_N (1.0f / 1024.0f)
#define LDSPITCH 132  // 128 + 4: breaks power-of-2 LDS row stride, keeps 16B alignment

// ---------------------------------------------------------------------------
// Kernel A: hs' = source @ W1[:256] + b1 ; ht = target @ W1[256:]
// 256 blocks x 256 threads; blocks 0..7 also zero rowsum[1024] ++ tcol[1024]
// (contiguous in ws) -- replaces the memset node (~4.5 us graph cost).
// ---------------------------------------------------------------------------
__global__ __launch_bounds__(256) void kA(const float* __restrict__ src,
                                          const float* __restrict__ tgt,
                                          const float* __restrict__ W1,
                                          const float* __restrict__ b1,
                                          float* __restrict__ hsp,
                                          float* __restrict__ htp,
                                          float* __restrict__ zeroBuf) {
    __shared__ float s[8 * EMBED];  // 8 KB: 8 staged input rows
    const int b = blockIdx.x;
    const int tid = threadIdx.x;

    if (b < 8) zeroBuf[b * 256 + tid] = 0.0f;  // zero rowsum+tcol (2048 floats)

    const bool isSrc = (b < 128);
    const int r0 = (isSrc ? b : b - 128) * 8;
    const float* __restrict__ in = isSrc ? src : tgt;
    const float* __restrict__ w = W1 + (isSrc ? 0 : EMBED * HID);
    float* __restrict__ outp = isSrc ? hsp : htp;

    {   // stage 8 rows = 2048 floats = 512 float4
        const float4* g = (const float4*)(in + r0 * EMBED);
        float4* sv = (float4*)s;
        sv[tid] = g[tid];
        sv[tid + 256] = g[tid + 256];
    }
    __syncthreads();

    const int h = tid & 127;
    const int rr = tid >> 7;  // 0 or 1
    float acc0 = 0.f, acc1 = 0.f, acc2 = 0.f, acc3 = 0.f;

    for (int k = 0; k < EMBED; k += 4) {
        const float w0 = w[(k + 0) * HID + h];
        const float w1v = w[(k + 1) * HID + h];
        const float w2v = w[(k + 2) * HID + h];
        const float w3v = w[(k + 3) * HID + h];
        const float4 s0 = *(const float4*)&s[(rr + 0) * EMBED + k];
        const float4 s1 = *(const float4*)&s[(rr + 2) * EMBED + k];
        const float4 s2 = *(const float4*)&s[(rr + 4) * EMBED + k];
        const float4 s3 = *(const float4*)&s[(rr + 6) * EMBED + k];
        acc0 = fmaf(s0.x, w0, acc0); acc0 = fmaf(s0.y, w1v, acc0);
        acc0 = fmaf(s0.z, w2v, acc0); acc0 = fmaf(s0.w, w3v, acc0);
        acc1 = fmaf(s1.x, w0, acc1); acc1 = fmaf(s1.y, w1v, acc1);
        acc1 = fmaf(s1.z, w2v, acc1); acc1 = fmaf(s1.w, w3v, acc1);
        acc2 = fmaf(s2.x, w0, acc2); acc2 = fmaf(s2.y, w1v, acc2);
        acc2 = fmaf(s2.z, w2v, acc2); acc2 = fmaf(s2.w, w3v, acc2);
        acc3 = fmaf(s3.x, w0, acc3); acc3 = fmaf(s3.y, w1v, acc3);
        acc3 = fmaf(s3.z, w2v, acc3); acc3 = fmaf(s3.w, w3v, acc3);
    }

    const float bias = isSrc ? b1[h] : 0.0f;
    outp[(r0 + rr + 0) * HID + h] = acc0 + bias;
    outp[(r0 + rr + 2) * HID + h] = acc1 + bias;
    outp[(r0 + rr + 4) * HID + h] = acc2 + bias;
    outp[(r0 + rr + 6) * HID + h] = acc3 + bias;
}

// ---------------------------------------------------------------------------
// Kernel B: fused cost network + rowsum of K.
//   C[i,j] = sum_h relu(hs'[i,h] + ht[j,h]) * W2[h] + b2
//   rowsum[i] += sum_j exp(-C[i,j])        (native exp in epilogue)
// 64x64 tile per block, 256 threads (16x16), 4x4 register blocking.
// ---------------------------------------------------------------------------
__global__ __launch_bounds__(256) void kB(const float* __restrict__ hsp,
                                          const float* __restrict__ htp,
                                          const float* __restrict__ W2,
                                          const float* __restrict__ b2,
                                          float* __restrict__ Cout,
                                          float* __restrict__ rowsum) {
    __shared__ float hsL[64 * LDSPITCH];  // 33 KB
    __shared__ float htL[64 * LDSPITCH];  // 33 KB
    __shared__ float w2L[HID];
    __shared__ float rsL[64];

    const int j0 = blockIdx.x * 64;
    const int i0 = blockIdx.y * 64;
    const int tid = threadIdx.x;

    for (int idx = tid; idx < 64 * 32; idx += 256) {
        const int i = idx >> 5;
        const int h4 = (idx & 31) << 2;
        *(float4*)&hsL[i * LDSPITCH + h4] = *(const float4*)&hsp[(i0 + i) * HID + h4];
        *(float4*)&htL[i * LDSPITCH + h4] = *(const float4*)&htp[(j0 + i) * HID + h4];
    }
    if (tid < HID) w2L[tid] = W2[tid];
    if (tid < 64) rsL[tid] = 0.0f;
    __syncthreads();

    const int ti = tid & 15;
    const int tj = tid >> 4;
    float acc[4][4] = {};

    for (int h = 0; h < HID; h += 4) {
        const float4 A0 = *(const float4*)&hsL[(ti + 0) * LDSPITCH + h];
        const float4 A1 = *(const float4*)&hsL[(ti + 16) * LDSPITCH + h];
        const float4 A2 = *(const float4*)&hsL[(ti + 32) * LDSPITCH + h];
        const float4 A3 = *(const float4*)&hsL[(ti + 48) * LDSPITCH + h];
        const float4 B0 = *(const float4*)&htL[(tj + 0) * LDSPITCH + h];
        const float4 B1 = *(const float4*)&htL[(tj + 16) * LDSPITCH + h];
        const float4 B2 = *(const float4*)&htL[(tj + 32) * LDSPITCH + h];
        const float4 B3 = *(const float4*)&htL[(tj + 48) * LDSPITCH + h];
        const float4 wv = *(const float4*)&w2L[h];
#define STEP(a, bb, Av, Bv)                                                    \
        {                                                                      \
            float t;                                                           \
            t = Av.x + Bv.x; acc[a][bb] = fmaf(fmaxf(t, 0.f), wv.x, acc[a][bb]); \
            t = Av.y + Bv.y; acc[a][bb] = fmaf(fmaxf(t, 0.f), wv.y, acc[a][bb]); \
            t = Av.z + Bv.z; acc[a][bb] = fmaf(fmaxf(t, 0.f), wv.z, acc[a][bb]); \
            t = Av.w + Bv.w; acc[a][bb] = fmaf(fmaxf(t, 0.f), wv.w, acc[a][bb]); \
        }
        STEP(0, 0, A0, B0) STEP(0, 1, A0, B1) STEP(0, 2, A0, B2) STEP(0, 3, A0, B3)
        STEP(1, 0, A1, B0) STEP(1, 1, A1, B1) STEP(1, 2, A1, B2) STEP(1, 3, A1, B3)
        STEP(2, 0, A2, B0) STEP(2, 1, A2, B1) STEP(2, 2, A2, B2) STEP(2, 3, A2, B3)
        STEP(3, 0, A3, B0) STEP(3, 1, A3, B1) STEP(3, 2, A3, B2) STEP(3, 3, A3, B3)
#undef STEP
    }

    const float b2v = b2[0];
    float rp[4] = {0.f, 0.f, 0.f, 0.f};
    for (int a = 0; a < 4; ++a) {
        const int i = i0 + ti + 16 * a;
        for (int bb = 0; bb < 4; ++bb) {
            const int j = j0 + tj + 16 * bb;
            const float c = acc[a][bb] + b2v;
            Cout[i * NN + j] = c;
            rp[a] += __expf(-c);
        }
    }
    for (int a = 0; a < 4; ++a) atomicAdd(&rsL[ti + 16 * a], rp[a]);
    __syncthreads();
    if (tid < 64) atomicAdd(&rowsum[i0 + tid], rsL[tid]);
}

// ---------------------------------------------------------------------------
// Kernel C: t[j] = sum_i exp(-C[i,j]) * u[i],  u[i] = 1/(rowsum[i] + NN*EPS).
// u precomputed once per block into LDS (broadcast reads, no per-thread div).
// 256 blocks: jb = b&3 -> 256 cols, ic = b>>2 -> 16-row chunk.
// ---------------------------------------------------------------------------
__global__ __launch_bounds__(256) void kC(const float* __restrict__ Cmat,
                                          const float* __restrict__ rowsum,
                                          float* __restrict__ tcol) {
    __shared__ float uL[16];
    const int b = blockIdx.x;
    const int jb = b & 3;
    const int ic = b >> 2;
    const int tid = threadIdx.x;
    if (tid < 16) {
        uL[tid] = __builtin_amdgcn_rcpf(rowsum[ic * 16 + tid] + NEPS);
    }
    __syncthreads();
    const int j = jb * 256 + tid;
    float acc = 0.f;
#pragma unroll
    for (int ii = 0; ii < 16; ++ii) {
        const float c = Cmat[(ic * 16 + ii) * NN + j];
        acc = fmaf(__expf(-c), uL[ii], acc);
    }
    atomicAdd(&tcol[j], acc);
}

// ---------------------------------------------------------------------------
// Kernel D: plan[i,j] = u[i] * exp(-C[i,j]) * v[j],
// u[i] = 1/(rowsum[i]+NN*EPS), v[j] = INV_N/(t[j]+EPS).  Native rcp/exp.
// ---------------------------------------------------------------------------
__global__ __launch_bounds__(256) void kD(const float* __restrict__ Cmat,
                                          const float* __restrict__ rowsum,
                                          const float* __restrict__ tcol,
                                          float* __restrict__ plan) {
    const int i0 = blockIdx.x * 4;
    const int tid = threadIdx.x;
    const int j4 = tid * 4;
    const float4 t4 = *(const float4*)&tcol[j4];
    float4 v4;
    v4.x = INV_N * __builtin_amdgcn_rcpf(t4.x + EPS);
    v4.y = INV_N * __builtin_amdgcn_rcpf(t4.y + EPS);
    v4.z = INV_N * __builtin_amdgcn_rcpf(t4.z + EPS);
    v4.w = INV_N * __builtin_amdgcn_rcpf(t4.w + EPS);
#pragma unroll
    for (int r = 0; r < 4; ++r) {
        const int row = i0 + r;
        const float u = __builtin_amdgcn_rcpf(rowsum[row] + NEPS);
        const float4 c4 = *(const float4*)&Cmat[row * NN + j4];
        float4 p;
        p.x = u * __expf(-c4.x) * v4.x;
        p.y = u * __expf(-c4.y) * v4.y;
        p.z = u * __expf(-c4.z) * v4.z;
        p.w = u * __expf(-c4.w) * v4.w;
        *(float4*)&plan[row * NN + j4] = p;
    }
}

// ---------------------------------------------------------------------------
extern "C" void kernel_launch(void* const* d_in, const int* in_sizes, int n_in,
                              void* d_out, int out_size, void* d_ws, size_t ws_size,
                              hipStream_t stream) {
    const float* src = (const float*)d_in[0];   // [1024, 256]
    const float* tgt = (const float*)d_in[1];   // [1024, 256]
    const float* W1  = (const float*)d_in[2];   // [512, 128]
    const float* b1  = (const float*)d_in[3];   // [128]
    const float* W2  = (const float*)d_in[4];   // [128, 1]
    const float* b2  = (const float*)d_in[5];   // [1]

    float* out = (float*)d_out;
    float* plan = out;            // [1024, 1024] (output 0)
    float* Cmat = out + NN * NN;  // [1024, 1024] (output 1)

    float* ws = (float*)d_ws;
    float* hsp    = ws;                 // [1024][128]
    float* htp    = ws + NN * HID;      // [1024][128]
    float* rowsum = ws + 2 * NN * HID;  // [1024]
    float* tcol   = rowsum + NN;        // [1024]
    // rowsum & tcol (contiguous 2048 floats) are zeroed by kA blocks 0..7.

    kA<<<256, 256, 0, stream>>>(src, tgt, W1, b1, hsp, htp, rowsum);
    kB<<<dim3(16, 16), 256, 0, stream>>>(hsp, htp, W2, b2, Cmat, rowsum);
    kC<<<256, 256, 0, stream>>>(Cmat, rowsum, tcol);
    kD<<<256, 256, 0, stream>>>(Cmat, rowsum, tcol, plan);
}